// Round 9
// baseline (344.243 us; speedup 1.0000x reference)
//
#include <hip/hip_runtime.h>
#include <hip/hip_bf16.h>
#include <stdint.h>

typedef __bf16 v8bf __attribute__((ext_vector_type(8)));
typedef float f32x4 __attribute__((ext_vector_type(4)));

__device__ __forceinline__ void gload_lds16(const void* g, void* l) {
    __builtin_amdgcn_global_load_lds(
        (const __attribute__((address_space(1))) void*)g,
        (__attribute__((address_space(3))) void*)l, 16, 0, 0);
}

__device__ __forceinline__ unsigned short f2bf(float f) {
    __hip_bfloat16 h = __float2bfloat16(f);
    return __builtin_bit_cast(unsigned short, h);
}

// ---- fused conversion: xc = concat(x,c) bf16 [8][2048][512]; Wbf = 4 weights
__global__ __launch_bounds__(256) void cvt_xcw(const float* __restrict__ x,
                                               const float* __restrict__ c,
                                               const float* __restrict__ wq,
                                               const float* __restrict__ wk,
                                               const float* __restrict__ wv,
                                               const float* __restrict__ wp,
                                               __hip_bfloat16* __restrict__ xc,
                                               __hip_bfloat16* __restrict__ wout) {
    int bid = blockIdx.x;
    if (bid < 8192) {
        int i = bid * 256 + threadIdx.x;
        long e = (long)i * 4;
        int b = (int)(e >> 20);
        int rem = (int)(e & ((1 << 20) - 1));
        int r = rem >> 9;
        int col = rem & 511;
        const float* src = (r < 1024) ? (x + ((long)b << 19) + (long)r * 512 + col)
                                      : (c + ((long)b << 19) + (long)(r - 1024) * 512 + col);
        float4 v = *(const float4*)src;
        ushort4 o;
        o.x = f2bf(v.x); o.y = f2bf(v.y); o.z = f2bf(v.z); o.w = f2bf(v.w);
        ((ushort4*)xc)[i] = o;
    } else {
        int i = (bid - 8192) * 256 + threadIdx.x;
        int e = i * 4;
        int w = e >> 18;
        int off = e & ((1 << 18) - 1);
        const float* src = (w == 0 ? wq : w == 1 ? wk : w == 2 ? wv : wp) + off;
        float4 val = *(const float4*)src;
        ushort4 o;
        o.x = f2bf(val.x); o.y = f2bf(val.y); o.z = f2bf(val.z); o.w = f2bf(val.w);
        ((ushort4*)wout)[i] = o;
    }
}

// mask int32 [8][1024][2048] -> bit-packed TRANSPOSED uint64 [8][word 32][q 1024]
__global__ __launch_bounds__(256) void cvt_mask(const int* __restrict__ mask,
                                                unsigned long long* __restrict__ mbt) {
    int t = threadIdx.x;
    long base = (long)blockIdx.x * 1024;
#pragma unroll
    for (int j = 0; j < 4; j++) {
        long i = base + j * 256 + t;            // [b][q][key] linear
        int v = mask[i] != 0;
        unsigned long long bits = __ballot(v);
        if ((t & 63) == 0) {
            int b = (int)(i >> 21);
            int q = (int)((i >> 11) & 1023);
            int word = (int)((i >> 6) & 31);
            mbt[((long)b * 32 + word) * 1024 + q] = bits;
        }
    }
}

// ---- fused QKV projection GEMM ------------------------------------------
// C[m,n] = sum_k xc[m,k]*Wbf[n,k], M=16384, N=1536. by<8: Q/K head-split
// scatter; Q pre-scaled by 0.125*log2e (softmax scale folded, exp2 path).
// by>=8 (V): LDS transpose -> coalesced V^T stores.
__global__ __launch_bounds__(256) void gemm_qkv(const __hip_bfloat16* __restrict__ A,
                                                const __hip_bfloat16* __restrict__ Bw,
                                                __hip_bfloat16* __restrict__ Qw,
                                                __hip_bfloat16* __restrict__ Kw,
                                                __hip_bfloat16* __restrict__ Vtw) {
    __shared__ union {
        struct { __hip_bfloat16 As[128 * 32]; __hip_bfloat16 Bs[128 * 32]; } s;
        __hip_bfloat16 T[128 * 136];
    } u;
    const int tid = threadIdx.x;
    const int wave = tid >> 6, lane = tid & 63;
    const int m0 = blockIdx.x * 128, n0 = blockIdx.y * 128;

    const int la = lane >> 2;
    const int kc = (lane & 3) * 8;
    const long ga0 = (long)(m0 + wave * 16 + la) * 512 + kc;
    const long ga1 = (long)(m0 + (wave + 4) * 16 + la) * 512 + kc;
    const long gb0 = (long)(n0 + wave * 16 + la) * 512 + kc;
    const long gb1 = (long)(n0 + (wave + 4) * 16 + la) * 512 + kc;

    f32x4 acc[4][4] = {};
    const int mw = (wave & 1) * 64, nw = (wave >> 1) * 64;
    const int lrow = lane & 15, lk = (lane >> 4) * 8;

    for (int k0 = 0; k0 < 512; k0 += 32) {
        gload_lds16(A + ga0 + k0, &u.s.As[wave * 512]);
        gload_lds16(A + ga1 + k0, &u.s.As[(wave + 4) * 512]);
        gload_lds16(Bw + gb0 + k0, &u.s.Bs[wave * 512]);
        gload_lds16(Bw + gb1 + k0, &u.s.Bs[(wave + 4) * 512]);
        __syncthreads();
        v8bf a[4], b[4];
#pragma unroll
        for (int i = 0; i < 4; i++) {
            a[i] = *(const v8bf*)&u.s.As[(mw + i * 16 + lrow) * 32 + lk];
            b[i] = *(const v8bf*)&u.s.Bs[(nw + i * 16 + lrow) * 32 + lk];
        }
#pragma unroll
        for (int mi = 0; mi < 4; mi++)
#pragma unroll
            for (int ni = 0; ni < 4; ni++)
                acc[mi][ni] = __builtin_amdgcn_mfma_f32_16x16x32_bf16(a[mi], b[ni], acc[mi][ni], 0, 0, 0);
        __syncthreads();
    }

    const int lq = lane >> 4;
    if (blockIdx.y < 8) {
#pragma unroll
        for (int mi = 0; mi < 4; mi++)
#pragma unroll
            for (int ni = 0; ni < 4; ni++)
#pragma unroll
                for (int r = 0; r < 4; r++) {
                    int grow = m0 + mw + mi * 16 + lq * 4 + r;
                    int gcol = n0 + nw + ni * 16 + lrow;
                    int w = gcol >> 9, g9 = gcol & 511;
                    int h = g9 >> 6, dh = g9 & 63;
                    int b_ = grow >> 11, rr = grow & 2047;
                    float val = acc[mi][ni][r];
                    if (w == 0) {
                        if (rr < 1024)
                            Qw[((long)(b_ * 8 + h) * 1024 + rr) * 64 + dh] =
                                __float2bfloat16(val * 0.1803368801f);  // 0.125*log2(e)
                    } else {
                        Kw[((long)(b_ * 8 + h) * 2048 + rr) * 64 + dh] = __float2bfloat16(val);
                    }
                }
    } else {
#pragma unroll
        for (int mi = 0; mi < 4; mi++)
#pragma unroll
            for (int ni = 0; ni < 4; ni++) {
                int n_l = nw + ni * 16 + lrow;
                int m_l = mw + mi * 16 + lq * 4;
                ushort4 pk;
                pk.x = f2bf(acc[mi][ni][0]); pk.y = f2bf(acc[mi][ni][1]);
                pk.z = f2bf(acc[mi][ni][2]); pk.w = f2bf(acc[mi][ni][3]);
                *(ushort4*)&u.T[n_l * 136 + m_l] = pk;
            }
        __syncthreads();
        const int no = (blockIdx.y - 8) * 128;
        const int b_ = m0 >> 11, rrb = m0 & 2047;
#pragma unroll
        for (int i = 0; i < 8; i++) {
            int s = tid + i * 256;
            int n_l = s >> 4, ch = s & 15;
            int ng = no + n_l;
            int h = ng >> 6, dh = ng & 63;
            uint4 v = *(const uint4*)&u.T[n_l * 136 + ch * 8];
            *(uint4*)&Vtw[((long)(b_ * 8 + h) * 64 + dh) * 2048 + rrb + ch * 8] = v;
        }
    }
}

// ---- output projection GEMM: d_out[m,n] = sum_k Yb[m,k]*Wp[n,k], fp32 out
__global__ __launch_bounds__(256) void gemm_out(const __hip_bfloat16* __restrict__ A,
                                                const __hip_bfloat16* __restrict__ Bw,
                                                float* __restrict__ outp) {
    __shared__ __hip_bfloat16 As[128 * 32];
    __shared__ __hip_bfloat16 Bs[128 * 32];
    const int tid = threadIdx.x;
    const int wave = tid >> 6, lane = tid & 63;
    const int m0 = blockIdx.x * 128, n0 = blockIdx.y * 128;

    const int la = lane >> 2;
    const int kc = (lane & 3) * 8;
    const long ga0 = (long)(m0 + wave * 16 + la) * 512 + kc;
    const long ga1 = (long)(m0 + (wave + 4) * 16 + la) * 512 + kc;
    const long gb0 = (long)(n0 + wave * 16 + la) * 512 + kc;
    const long gb1 = (long)(n0 + (wave + 4) * 16 + la) * 512 + kc;

    f32x4 acc[4][4] = {};
    const int mw = (wave & 1) * 64, nw = (wave >> 1) * 64;
    const int lrow = lane & 15, lk = (lane >> 4) * 8;

    for (int k0 = 0; k0 < 512; k0 += 32) {
        gload_lds16(A + ga0 + k0, &As[wave * 512]);
        gload_lds16(A + ga1 + k0, &As[(wave + 4) * 512]);
        gload_lds16(Bw + gb0 + k0, &Bs[wave * 512]);
        gload_lds16(Bw + gb1 + k0, &Bs[(wave + 4) * 512]);
        __syncthreads();
        v8bf a[4], b[4];
#pragma unroll
        for (int i = 0; i < 4; i++) {
            a[i] = *(const v8bf*)&As[(mw + i * 16 + lrow) * 32 + lk];
            b[i] = *(const v8bf*)&Bs[(nw + i * 16 + lrow) * 32 + lk];
        }
#pragma unroll
        for (int mi = 0; mi < 4; mi++)
#pragma unroll
            for (int ni = 0; ni < 4; ni++)
                acc[mi][ni] = __builtin_amdgcn_mfma_f32_16x16x32_bf16(a[mi], b[ni], acc[mi][ni], 0, 0, 0);
        __syncthreads();
    }

    const int lq = lane >> 4;
#pragma unroll
    for (int mi = 0; mi < 4; mi++)
#pragma unroll
        for (int ni = 0; ni < 4; ni++)
#pragma unroll
            for (int r = 0; r < 4; r++) {
                int grow = m0 + mw + mi * 16 + lq * 4 + r;
                int gcol = n0 + nw + ni * 16 + lrow;
                outp[(long)grow * 512 + gcol] = acc[mi][ni][r];
            }
}

// ---- flash attention v4: 32-q blocks, key-split S, d-split PV ------------
// grid 2048 (b=L&7 XCD-pinned, qt=(L>>3)&31, h=L>>8). Block 4 waves, 32 q,
// 128 keys/iter. S: wave w owns keys w*32+[0,32) (2 sub-tiles g), K frags
// direct from global. exp2 (scale folded into Q), nibble mask test, packed
// bf16 cvt. P in shared LDS [32q][128k] XOR-swizzled. PV: wave w owns
// d-slice w*16+[0,16) for all q -> Oacc[2] (8 regs). Mask transposed ->
// 2 coalesced broadcast u64 loads per iter.
__global__ __launch_bounds__(256) void flash(const __hip_bfloat16* __restrict__ Q,
                                             const __hip_bfloat16* __restrict__ K,
                                             const __hip_bfloat16* __restrict__ Vt,
                                             const unsigned long long* __restrict__ Mbt,
                                             __hip_bfloat16* __restrict__ Y) {
    __shared__ __hip_bfloat16 Ps[32 * 128];   // 8KB, [q][key], 16B chunks XOR (q&7)
    __shared__ float Ls[4][32];

    const int L = blockIdx.x;
    const int b = L & 7, qt = (L >> 3) & 31, h = L >> 8;
    const int bh = b * 8 + h;
    const int tid = threadIdx.x, w = tid >> 6, lane = tid & 63;
    const int lcol = lane & 15, lq = lane >> 4;

    const __hip_bfloat16* Qp = Q + ((long)bh * 1024 + qt * 32) * 64;
    const __hip_bfloat16* Kp = K + ((long)bh * 2048 + w * 32 + lcol) * 64;   // S A-frag rows
    const __hip_bfloat16* Vp = Vt + ((long)bh * 64 + w * 16 + lcol) * 2048;  // PV B-frag rows
    // transposed mask: word = kt*2 + (w>>1); element q = qt*32 + mi*16 + lcol
    const unsigned long long* Mp = Mbt + ((long)b * 32 + (w >> 1)) * 1024 + qt * 32 + lcol;

    // Q B-frags (32 q), register-resident; Q pre-scaled by 0.125*log2e
    v8bf bq[2][2];
#pragma unroll
    for (int mi = 0; mi < 2; mi++)
#pragma unroll
        for (int ks = 0; ks < 2; ks++)
            bq[mi][ks] = *(const v8bf*)(Qp + (mi * 16 + lcol) * 64 + ks * 32 + lq * 8);

    f32x4 Oacc[2] = {};
    float lsum[2] = {0.f, 0.f};
    const int gsh = (2 * w) & 3;   // sub-word base for g=0 ((2w+g)&3 = gsh+g)

    for (int kt = 0; kt < 16; kt++) {
        // coalesced broadcast mask words (2 loads)
        unsigned long long mw_[2];
#pragma unroll
        for (int mi = 0; mi < 2; mi++)
            mw_[mi] = Mp[(long)kt * 2048 + mi * 16];

        // K A-frags (this wave's 32 keys)
        v8bf ak[2][2];
#pragma unroll
        for (int g = 0; g < 2; g++)
#pragma unroll
            for (int ks = 0; ks < 2; ks++)
                ak[g][ks] = *(const v8bf*)(Kp + (long)(kt * 128 + g * 16) * 64 + ks * 32 + lq * 8);

        // V B-frags (consumed after barrier; latency hides under S+exp)
        v8bf bv[4];
#pragma unroll
        for (int kc = 0; kc < 4; kc++)
            bv[kc] = *(const v8bf*)(Vp + kt * 128 + kc * 32 + lq * 8);

        // S^T = K Q^T; exp2; P -> shared LDS
#pragma unroll
        for (int g = 0; g < 2; g++)
#pragma unroll
            for (int mi = 0; mi < 2; mi++) {
                f32x4 st = {};
                st = __builtin_amdgcn_mfma_f32_16x16x32_bf16(ak[g][0], bq[mi][0], st, 0, 0, 0);
                st = __builtin_amdgcn_mfma_f32_16x16x32_bf16(ak[g][1], bq[mi][1], st, 0, 0, 0);
                unsigned int m4 = (unsigned int)(mw_[mi] >> ((gsh + g) * 16 + lq * 4)) & 0xFu;
                float e[4];
#pragma unroll
                for (int r = 0; r < 4; r++) {
                    float s = fminf(st[r], 57.f);
                    float ex = __builtin_amdgcn_exp2f(s);
                    ex = ((m4 >> r) & 1u) ? 0.f : ex;
                    lsum[mi] += ex;
                    e[r] = ex;
                }
                __hip_bfloat162 lo = __float22bfloat162_rn(make_float2(e[0], e[1]));
                __hip_bfloat162 hi = __float22bfloat162_rn(make_float2(e[2], e[3]));
                uint2 pk;
                __builtin_memcpy(&pk.x, &lo, 4);
                __builtin_memcpy(&pk.y, &hi, 4);
                int q = mi * 16 + lcol;
                int cw = (w * 4 + g * 2 + (lq >> 1)) ^ (q & 7);
                *(uint2*)((char*)Ps + q * 256 + cw * 16 + (lq & 1) * 8) = pk;
            }
        __syncthreads();

        // PV: wave w's 16-d slice over all 32 q
#pragma unroll
        for (int mi = 0; mi < 2; mi++) {
            int q = mi * 16 + lcol;
#pragma unroll
            for (int kc = 0; kc < 4; kc++) {
                v8bf ap = *(const v8bf*)((char*)Ps + q * 256 + (((kc * 4 + lq) ^ (q & 7)) * 16));
                Oacc[mi] = __builtin_amdgcn_mfma_f32_16x16x32_bf16(ap, bv[kc], Oacc[mi], 0, 0, 0);
            }
        }
        __syncthreads();
    }

    // lsum: reduce over lq groups, publish per-wave partials
#pragma unroll
    for (int mi = 0; mi < 2; mi++) {
        float s = lsum[mi];
        s += __shfl_xor(s, 16);
        s += __shfl_xor(s, 32);
        lsum[mi] = s;
    }
    if (lq == 0) {
#pragma unroll
        for (int mi = 0; mi < 2; mi++) Ls[w][mi * 16 + lcol] = lsum[mi];
    }
    __syncthreads();

    // epilogue: wave stores its own d-slice (C-layout rows q = mi*16+lq*4+r)
#pragma unroll
    for (int mi = 0; mi < 2; mi++) {
#pragma unroll
        for (int r = 0; r < 4; r++) {
            int q = mi * 16 + lq * 4 + r;
            float rs = Ls[0][q] + Ls[1][q] + Ls[2][q] + Ls[3][q];
            float inv = 1.f / rs;
            long row = (long)b * 1024 + qt * 32 + q;
            Y[row * 512 + h * 64 + w * 16 + lcol] = __float2bfloat16(Oacc[mi][r] * inv);
        }
    }
}

// ---- launch -------------------------------------------------------------
extern "C" void kernel_launch(void* const* d_in, const int* in_sizes, int n_in,
                              void* d_out, int out_size, void* d_ws, size_t ws_size,
                              hipStream_t stream) {
    const float* x = (const float*)d_in[0];
    const float* c = (const float*)d_in[1];
    const int* mask = (const int*)d_in[2];
    const float* Wq = (const float*)d_in[3];
    const float* Wk = (const float*)d_in[4];
    const float* Wv = (const float*)d_in[5];
    const float* Wp = (const float*)d_in[6];

    char* ws = (char*)d_ws;
    __hip_bfloat16* xc  = (__hip_bfloat16*)(ws);                 // 16 MB (dead after gemm_qkv)
    __hip_bfloat16* Wbf = (__hip_bfloat16*)(ws + 16777216);      //  2 MB
    __hip_bfloat16* Qw  = (__hip_bfloat16*)(ws + 18874368);      //  8 MB
    __hip_bfloat16* Kw  = (__hip_bfloat16*)(ws + 27262976);      // 16 MB
    __hip_bfloat16* Vtw = (__hip_bfloat16*)(ws + 44040192);      // 16 MB
    __hip_bfloat16* Yb  = (__hip_bfloat16*)(ws + 60817408);      //  8 MB
    unsigned long long* Mbp = (unsigned long long*)(ws);         //  2 MB, aliases dead xc

    cvt_xcw<<<9216, 256, 0, stream>>>(x, c, Wq, Wk, Wv, Wp, xc, Wbf);
    gemm_qkv<<<dim3(128, 12), 256, 0, stream>>>(xc, Wbf, Qw, Kw, Vtw);
    cvt_mask<<<16384, 256, 0, stream>>>(mask, Mbp);   // after gemm_qkv: overwrites xc
    flash<<<2048, 256, 0, stream>>>(Qw, Kw, Vtw, Mbp, Yb);
    gemm_out<<<dim3(64, 4), 256, 0, stream>>>(Yb, Wbf + 3 * 262144, (float*)d_out);
}